// Round 8
// baseline (684.164 us; speedup 1.0000x reference)
//
#include <hip/hip_runtime.h>
#include <math.h>

#define LVL 24
#define TMASK ((1u << 19) - 1u)

typedef short short8 __attribute__((ext_vector_type(8)));
typedef float floatx4 __attribute__((ext_vector_type(4)));

struct ResParams { float r[LVL]; };

__device__ __forceinline__ float bf2f(unsigned short b) {
  union { unsigned u; float f; } t; t.u = ((unsigned)b) << 16; return t.f;
}
__device__ __forceinline__ unsigned f2bf(float f) {
  union { float f; unsigned u; } t; t.f = f;
  unsigned u = t.u;
  u += 0x7FFFu + ((u >> 16) & 1u);   // RNE
  return u >> 16;
}
// Fast exact-form gelu: A&S 7.1.26 erf, |err| < 1.5e-7, branch-free.
__device__ __forceinline__ float geluf(float x) {
  float a = fabsf(x) * 0.7071067811865476f;
  float t = __builtin_amdgcn_rcpf(fmaf(0.3275911f, a, 1.0f));
  float p = fmaf(t, 1.061405429f, -1.453152027f);
  p = fmaf(t, p, 1.421413741f);
  p = fmaf(t, p, -0.284496736f);
  p = fmaf(t, p, 0.254829592f);
  float er = 1.0f - p * t * __expf(-a * a);
  return 0.5f * x * (1.0f + copysignf(er, x));
}
__device__ __forceinline__ floatx4 mfma16(short8 a, short8 b, floatx4 c) {
  return __builtin_amdgcn_mfma_f32_16x16x32_bf16(a, b, c, 0, 0, 0);
}

// Fragment-ordered weight image offsets (shorts / short8).
#define L0_W 0
#define L1_W 4096
#define L2_W 8192
#define L3_W 12288
#define L4_W 17408
#define L5_W 23552
#define L6_W 27648
#define L0_F 0
#define L1_F 512
#define L2_F 1024
#define L3_F 1536
#define L4_F 2176
#define L5_F 2944
#define L6_F 3456

// ---------------------------------------------------------------------------
// Prep: blocks 0-7 build fragment-ordered bf16 weight images + bias image;
// blocks 8+ pack the f32 table to bf16x2 (float4 -> uint2).
// ---------------------------------------------------------------------------
__device__ void prepF(const float* w, short* dst, int K, int NOUT, int KCH, int CBS) {
  int total = KCH * CBS * 64 * 8;
  for (int i = threadIdx.x; i < total; i += 256) {
    int j = i & 7;
    int lane = (i >> 3) & 63;
    int cbc = i >> 9;
    int cb = cbc % CBS;
    int c  = cbc / CBS;
    int n = cb * 16 + (lane & 15);
    int k = c * 32 + (lane >> 4) * 8 + j;
    short v = 0;
    if (k < K && n < NOUT) v = (short)f2bf(w[k * NOUT + n]);
    dst[i] = v;
  }
}
__global__ __launch_bounds__(256) void prep_all(
    const float* __restrict__ fw0, const float* __restrict__ fb0,
    const float* __restrict__ fw1, const float* __restrict__ fb1,
    const float* __restrict__ fw2, const float* __restrict__ fb2,
    const float* __restrict__ fw3, const float* __restrict__ fb3,
    const float* __restrict__ rw0, const float* __restrict__ rb0,
    const float* __restrict__ rw1, const float* __restrict__ rb1,
    const float* __restrict__ rw2, const float* __restrict__ rb2,
    short* __restrict__ Wimg, float* __restrict__ Bimg,
    const float* __restrict__ tbl, unsigned* __restrict__ tblq, int nent,
    int pack_on)
{
  int b = blockIdx.x, tid = threadIdx.x;
  if (b >= 8) {
    if (!pack_on) return;
    int g = (b - 8) * 256 + tid;
    int stride = (gridDim.x - 8) * 256;
    const float4* t4 = (const float4*)tbl;
    uint2* q2 = (uint2*)tblq;
    int n4 = nent >> 1;
    for (int e = g; e < n4; e += stride) {
      float4 v = t4[e];
      uint2 o;
      o.x = f2bf(v.x) | (f2bf(v.y) << 16);
      o.y = f2bf(v.z) | (f2bf(v.w) << 16);
      q2[e] = o;
    }
    return;
  }
  switch (b) {
    case 0: prepF(fw0, Wimg + L0_W, 48, 64, 2, 4); break;
    case 1: prepF(fw1, Wimg + L1_W, 64, 64, 2, 4); break;
    case 2: prepF(fw2, Wimg + L2_W, 64, 64, 2, 4); break;
    case 3: prepF(fw3, Wimg + L3_W, 64, 65, 2, 5); break;
    case 4: prepF(rw0, Wimg + L4_W, 73, 64, 3, 4); break;
    case 5: prepF(rw1, Wimg + L5_W, 64, 64, 2, 4); break;
    case 6: prepF(rw2, Wimg + L6_W, 64,  3, 2, 1); break;
    case 7:
      if (tid < 64) {
        Bimg[tid]       = fb0[tid];
        Bimg[64 + tid]  = fb1[tid];
        Bimg[128 + tid] = fb2[tid];
        Bimg[272 + tid] = rb0[tid];
        Bimg[336 + tid] = rb1[tid];
      }
      if (tid < 80) Bimg[192 + tid] = (tid < 65) ? fb3[tid] : 0.0f;
      if (tid < 16) Bimg[400 + tid] = (tid < 3) ? rb2[tid] : 0.0f;
      break;
  }
}

// ---------------------------------------------------------------------------
// Fused per-block kernel: each wave hash-encodes its own 32 rows straight
// into its LDS A-tile (level-pair inner order for L2 locality), then runs
// the 7-layer MFMA MLP. Encode-phase waves (gather-bound) co-schedule with
// mlp-phase waves (VALU/MFMA-bound) on each CU.
// ---------------------------------------------------------------------------
template<int KCH, int CBS>
__device__ __forceinline__ void run_layer32(const short* At, const short8* Wf,
                                            int lane, int m, int quad,
                                            floatx4* acc0, floatx4* acc1) {
  #pragma unroll
  for (int cb = 0; cb < CBS; ++cb) {
    acc0[cb] = (floatx4){0.f, 0.f, 0.f, 0.f};
    acc1[cb] = (floatx4){0.f, 0.f, 0.f, 0.f};
  }
  #pragma unroll
  for (int c = 0; c < KCH; ++c) {
    short8 a0 = *(const short8*)(At + m * 104 + c * 32 + quad * 8);
    short8 a1 = *(const short8*)(At + (16 + m) * 104 + c * 32 + quad * 8);
    #pragma unroll
    for (int cb = 0; cb < CBS; ++cb) {
      short8 b = Wf[(c * CBS + cb) * 64 + lane];
      acc0[cb] = mfma16(a0, b, acc0[cb]);
      acc1[cb] = mfma16(a1, b, acc1[cb]);
    }
  }
}

template<bool PACKED>
__global__ __launch_bounds__(256, 4) void nerf_block(
    const float* __restrict__ pts, const float* __restrict__ dirs,
    const float* __restrict__ tblf, const unsigned* __restrict__ tblq,
    const short* __restrict__ Wimg, const float* __restrict__ Bimg,
    float* __restrict__ outp, int Nrows, ResParams rp)
{
  __shared__ __align__(16) short Atile[4 * 32 * 104];
  __shared__ __align__(16) float Blds[416];
  __shared__ float pbuf[4][96];

  const int tid  = threadIdx.x;
  const int wave = tid >> 6;
  const int lane = tid & 63;
  const int m    = lane & 15;
  const int quad = lane >> 4;
  const int row0 = blockIdx.x * 128 + wave * 32;
  short* At = Atile + wave * (32 * 104);
  const short8* Wf = (const short8*)Wimg;

  if (tid < 104) ((float4*)Blds)[tid] = ((const float4*)Bimg)[tid];

  // stage this wave's 32 points (96 floats, coalesced)
  {
    const float* pf = pts + (size_t)row0 * 3;
    pbuf[wave][lane] = pf[lane];
    if (lane < 32) pbuf[wave][64 + lane] = pf[64 + lane];
  }

  // SH3 dirs at k=64..72, zeros k=48..63 / 73..103 (lanes 0..31 = 32 rows)
  if (lane < 32) {
    int row = row0 + lane;
    float dx = dirs[row * 3 + 0];
    float dy = dirs[row * 3 + 1];
    float dz = dirs[row * 3 + 2];
    short8 z8 = {0, 0, 0, 0, 0, 0, 0, 0};
    short8 s07;
    s07[0] = (short)f2bf(0.28209479177387814f);
    s07[1] = (short)f2bf(-0.48860251190291987f * dy);
    s07[2] = (short)f2bf(0.48860251190291987f * dz);
    s07[3] = (short)f2bf(-0.48860251190291987f * dx);
    s07[4] = (short)f2bf(1.0925484305920792f * dx * dy);
    s07[5] = (short)f2bf(-1.0925484305920792f * dy * dz);
    s07[6] = (short)f2bf(0.31539156525252005f * (3.0f * dz * dz - 1.0f));
    s07[7] = (short)f2bf(-1.0925484305920792f * dx * dz);
    short8 s8v = {0, 0, 0, 0, 0, 0, 0, 0};
    s8v[0] = (short)f2bf(0.5462742152960396f * (dx * dx - dy * dy));
    short* rb = At + lane * 104;
    *(short8*)(rb + 48) = z8;
    *(short8*)(rb + 56) = z8;
    *(short8*)(rb + 64) = s07;
    *(short8*)(rb + 72) = s8v;
    *(short8*)(rb + 80) = z8;
    *(short8*)(rb + 88) = z8;
    *(short8*)(rb + 96) = z8;
  }

  // ---- hash encode: 32 rows x 24 levels = 768 tasks, 12 iters x 64 lanes.
  // half-wave0 -> level 2it, half-wave1 -> level 2it+1 (locality by pairs).
  {
    const int r = lane & 31;
    const float px = pbuf[wave][r * 3 + 0];
    const float py = pbuf[wave][r * 3 + 1];
    const float pz = pbuf[wave][r * 3 + 2];
    #pragma unroll
    for (int it = 0; it < 12; ++it) {
      const int l = 2 * it + (lane >> 5);
      float res = (lane & 32) ? rp.r[2 * it + 1] : rp.r[2 * it];
      float x = (px + 1.0f) * 0.5f * res;
      float y = (py + 1.0f) * 0.5f * res;
      float z = (pz + 1.0f) * 0.5f * res;
      float fx = floorf(x), fy = floorf(y), fz = floorf(z);
      float w0 = x - fx, w1 = y - fy, w2 = z - fz;
      unsigned c0 = (unsigned)fx, c1 = (unsigned)fy, c2 = (unsigned)fz;
      unsigned hy0 = c1 * 2654435761u, hy1 = hy0 + 2654435761u;
      unsigned hz0 = c2 * 805459861u,  hz1 = hz0 + 805459861u;
      bool ceven = ((c0 & 1u) == 0u);
      unsigned lbase = (unsigned)l << 19;

      float f0 = 0.f, f1 = 0.f;
      #pragma unroll
      for (int yz = 0; yz < 4; ++yz) {
        unsigned hyz = ((yz & 2) ? hy1 : hy0) ^ ((yz & 1) ? hz1 : hz0);
        float wyz = ((yz & 2) ? w1 : 1.f - w1) * ((yz & 1) ? w2 : 1.f - w2);
        unsigned h0 = (c0 ^ hyz) & TMASK;
        unsigned h1 = ((c0 + 1u) ^ hyz) & TMASK;
        float e00, e01, e10, e11;
        if constexpr (PACKED) {
          unsigned v0, v1;
          if (ceven) {                           // h1 == h0^1
            uint2 v = *(const uint2*)(tblq + (size_t)(lbase | (h0 & ~1u)));
            v0 = (h0 & 1u) ? v.y : v.x;
            v1 = (h0 & 1u) ? v.x : v.y;
          } else {
            v0 = tblq[(size_t)(lbase | h0)];
            v1 = tblq[(size_t)(lbase | h1)];
          }
          e00 = bf2f((unsigned short)(v0 & 0xffffu)); e01 = bf2f((unsigned short)(v0 >> 16));
          e10 = bf2f((unsigned short)(v1 & 0xffffu)); e11 = bf2f((unsigned short)(v1 >> 16));
        } else {
          const float* tf = tblf + ((size_t)l << 20);
          if (ceven) {
            float4 v = *(const float4*)(tf + 2u * (h0 & ~1u));
            if (h0 & 1u) { e00 = v.z; e01 = v.w; e10 = v.x; e11 = v.y; }
            else         { e00 = v.x; e01 = v.y; e10 = v.z; e11 = v.w; }
          } else {
            float2 a = *(const float2*)(tf + 2u * h0);
            float2 b = *(const float2*)(tf + 2u * h1);
            e00 = a.x; e01 = a.y; e10 = b.x; e11 = b.y;
          }
        }
        float wa = (1.f - w0) * wyz, wb = w0 * wyz;
        f0 += wa * e00 + wb * e10;
        f1 += wa * e01 + wb * e11;
      }
      *(unsigned*)(At + r * 104 + 2 * l) = f2bf(f0) | (f2bf(f1) << 16);
    }
  }

  __syncthreads();   // Blds visibility (Atile/pbuf are wave-private)

  floatx4 acc0[5], acc1[5];

#define EPI_GELU(BOFF)                                                        \
  _Pragma("unroll")                                                           \
  for (int cb = 0; cb < 4; ++cb) {                                            \
    float bc = Blds[(BOFF) + cb * 16 + m];                                    \
    _Pragma("unroll")                                                         \
    for (int r = 0; r < 4; ++r) {                                             \
      At[(quad * 4 + r) * 104 + cb * 16 + m]      = (short)f2bf(geluf(acc0[cb][r] + bc)); \
      At[(16 + quad * 4 + r) * 104 + cb * 16 + m] = (short)f2bf(geluf(acc1[cb][r] + bc)); \
    }                                                                         \
  }

  // L0
  run_layer32<2, 4>(At, Wf + L0_F, lane, m, quad, acc0, acc1);
  EPI_GELU(0)
  // L1
  run_layer32<2, 4>(At, Wf + L1_F, lane, m, quad, acc0, acc1);
  EPI_GELU(64)
  // L2
  run_layer32<2, 4>(At, Wf + L2_F, lane, m, quad, acc0, acc1);
  EPI_GELU(128)
  // L3: col0 -> softplus -> density ; cols 1..64 -> gelu -> k=0..63
  run_layer32<2, 5>(At, Wf + L3_F, lane, m, quad, acc0, acc1);
  #pragma unroll
  for (int cb = 0; cb < 5; ++cb) {
    int col = cb * 16 + m;
    float bc = Blds[192 + col];
    #pragma unroll
    for (int r = 0; r < 4; ++r) {
      #pragma unroll
      for (int t = 0; t < 2; ++t) {
        float v = (t ? acc1[cb][r] : acc0[cb][r]) + bc;
        int row = t * 16 + quad * 4 + r;
        if (col == 0) {
          float d = (v > 15.f) ? v : __logf(1.0f + __expf(v));
          outp[3 * Nrows + row0 + row] = d;
        } else if (col <= 64) {
          At[row * 104 + (col - 1)] = (short)f2bf(geluf(v));
        }
      }
    }
  }
  // L4: [feat64 | sh9 | 0pad] (K=96) -> 64, gelu
  run_layer32<3, 4>(At, Wf + L4_F, lane, m, quad, acc0, acc1);
  EPI_GELU(272)
  // L5
  run_layer32<2, 4>(At, Wf + L5_F, lane, m, quad, acc0, acc1);
  EPI_GELU(336)
  // L6: 64 -> 3, sigmoid -> rgb
  run_layer32<2, 1>(At, Wf + L6_F, lane, m, quad, acc0, acc1);
  {
    float bc = Blds[400 + m];
    #pragma unroll
    for (int r = 0; r < 4; ++r) {
      #pragma unroll
      for (int t = 0; t < 2; ++t) {
        float v = (t ? acc1[0][r] : acc0[0][r]) + bc;
        float s = __builtin_amdgcn_rcpf(1.0f + __expf(-v));
        int row = t * 16 + quad * 4 + r;
        if (m < 3) outp[(row0 + row) * 3 + m] = s;
      }
    }
  }
#undef EPI_GELU
}

// ---------------------------------------------------------------------------
// Fallback: fully fused LDS-weight kernel (used only if ws too small).
// ---------------------------------------------------------------------------
#define W0_OFF 0
#define W1_OFF 4608
#define W2_OFF 9216
#define W3_OFF 13824
#define R0_OFF 0
#define R1_OFF 6656
#define R2_OFF 11264

template<int K, int NOUT, int NROWS, int STRIDE>
__device__ void stageW(const float* w, short* dst, int tid) {
  for (int i = tid; i < NROWS * STRIDE; i += 256) {
    int n = i / STRIDE;
    int k = i - n * STRIDE;
    short v = 0;
    if (n < NOUT && k < K) v = (short)f2bf(w[k * NOUT + n]);
    dst[i] = v;
  }
}
template<int NOUT, int NPAD>
__device__ void stageB(const float* b, float* dst, int tid) {
  for (int i = tid; i < NPAD; i += 256) dst[i] = (i < NOUT) ? b[i] : 0.0f;
}
template<int KCH, int CBS, int WSTRIDE>
__device__ __forceinline__ void run_layer(const short* At, const short* Wb,
                                          int m, int quad, floatx4* acc) {
  #pragma unroll
  for (int cb = 0; cb < CBS; ++cb) acc[cb] = (floatx4){0.f, 0.f, 0.f, 0.f};
  #pragma unroll
  for (int c = 0; c < KCH; ++c) {
    short8 a = *(const short8*)(At + m * 104 + c * 32 + quad * 8);
    #pragma unroll
    for (int cb = 0; cb < CBS; ++cb) {
      short8 b = *(const short8*)(Wb + (cb * 16 + m) * WSTRIDE + c * 32 + quad * 8);
      acc[cb] = mfma16(a, b, acc[cb]);
    }
  }
}

__global__ __launch_bounds__(256, 2) void nerf_fused(
    const float* __restrict__ pts,
    const float* __restrict__ dirs,
    const float* __restrict__ tbl,
    const float* __restrict__ fw0, const float* __restrict__ fb0,
    const float* __restrict__ fw1, const float* __restrict__ fb1,
    const float* __restrict__ fw2, const float* __restrict__ fb2,
    const float* __restrict__ fw3, const float* __restrict__ fb3,
    const float* __restrict__ rw0, const float* __restrict__ rb0,
    const float* __restrict__ rw1, const float* __restrict__ rb1,
    const float* __restrict__ rw2, const float* __restrict__ rb2,
    float* __restrict__ outp, int Nrows, ResParams rp)
{
  __shared__ __align__(16) short Wlds[19584];
  __shared__ __align__(16) float Blds[272];
  __shared__ __align__(16) short Atile[4 * 16 * 104];

  const int tid  = threadIdx.x;
  const int wave = tid >> 6;
  const int lane = tid & 63;
  const int m    = lane & 15;
  const int quad = lane >> 4;
  const int row0 = blockIdx.x * 64 + wave * 16;
  short* At = Atile + wave * (16 * 104);

  stageW<48, 64, 64, 72>(fw0, Wlds + W0_OFF, tid);
  stageW<64, 64, 64, 72>(fw1, Wlds + W1_OFF, tid);
  stageW<64, 64, 64, 72>(fw2, Wlds + W2_OFF, tid);
  stageW<64, 65, 80, 72>(fw3, Wlds + W3_OFF, tid);
  stageB<64, 64>(fb0, Blds + 0,   tid);
  stageB<64, 64>(fb1, Blds + 64,  tid);
  stageB<64, 64>(fb2, Blds + 128, tid);
  stageB<65, 80>(fb3, Blds + 192, tid);

  if (lane < 16) {
    int row = row0 + lane;
    float dx = dirs[row * 3 + 0];
    float dy = dirs[row * 3 + 1];
    float dz = dirs[row * 3 + 2];
    short8 z8 = {0, 0, 0, 0, 0, 0, 0, 0};
    short8 s07;
    s07[0] = (short)f2bf(0.28209479177387814f);
    s07[1] = (short)f2bf(-0.48860251190291987f * dy);
    s07[2] = (short)f2bf(0.48860251190291987f * dz);
    s07[3] = (short)f2bf(-0.48860251190291987f * dx);
    s07[4] = (short)f2bf(1.0925484305920792f * dx * dy);
    s07[5] = (short)f2bf(-1.0925484305920792f * dy * dz);
    s07[6] = (short)f2bf(0.31539156525252005f * (3.0f * dz * dz - 1.0f));
    s07[7] = (short)f2bf(-1.0925484305920792f * dx * dz);
    short8 s8v = {0, 0, 0, 0, 0, 0, 0, 0};
    s8v[0] = (short)f2bf(0.5462742152960396f * (dx * dx - dy * dy));
    short* rb = At + lane * 104;
    *(short8*)(rb + 48) = z8;
    *(short8*)(rb + 56) = z8;
    *(short8*)(rb + 64) = s07;
    *(short8*)(rb + 72) = s8v;
    *(short8*)(rb + 80) = z8;
    *(short8*)(rb + 88) = z8;
    *(short8*)(rb + 96) = z8;
  }

  for (int t = lane; t < 16 * LVL; t += 64) {
    int r = t / LVL;
    int l = t - r * LVL;
    int row = row0 + r;
    float res = rp.r[l];
    float x = (pts[row * 3 + 0] + 1.0f) * 0.5f * res;
    float y = (pts[row * 3 + 1] + 1.0f) * 0.5f * res;
    float z = (pts[row * 3 + 2] + 1.0f) * 0.5f * res;
    float fx = floorf(x), fy = floorf(y), fz = floorf(z);
    float w0 = x - fx, w1 = y - fy, w2 = z - fz;
    unsigned c0 = (unsigned)fx, c1 = (unsigned)fy, c2 = (unsigned)fz;
    unsigned ha0 = c0, hb0 = c0 + 1u;
    unsigned ha1 = c1 * 2654435761u, hb1 = ha1 + 2654435761u;
    unsigned ha2 = c2 * 805459861u,  hb2 = ha2 + 805459861u;
    const float* tb = tbl + ((size_t)l << 20);
    float f0 = 0.f, f1 = 0.f;
    #pragma unroll
    for (int i = 0; i < 8; ++i) {
      unsigned h = ((i & 4) ? hb0 : ha0) ^ ((i & 2) ? hb1 : ha1) ^ ((i & 1) ? hb2 : ha2);
      float wt = ((i & 4) ? w0 : 1.f - w0) * ((i & 2) ? w1 : 1.f - w1) * ((i & 1) ? w2 : 1.f - w2);
      float2 fv = *(const float2*)(tb + 2u * (h & TMASK));
      f0 += wt * fv.x;
      f1 += wt * fv.y;
    }
    unsigned pk = f2bf(f0) | (f2bf(f1) << 16);
    *(unsigned*)(At + r * 104 + 2 * l) = pk;
  }

  __syncthreads();

  floatx4 acc[5];

  run_layer<2, 4, 72>(At, Wlds + W0_OFF, m, quad, acc);
  #pragma unroll
  for (int cb = 0; cb < 4; ++cb) {
    float bc = Blds[0 + cb * 16 + m];
    #pragma unroll
    for (int r = 0; r < 4; ++r) {
      float v = geluf(acc[cb][r] + bc);
      At[(quad * 4 + r) * 104 + cb * 16 + m] = (short)f2bf(v);
    }
  }
  run_layer<2, 4, 72>(At, Wlds + W1_OFF, m, quad, acc);
  #pragma unroll
  for (int cb = 0; cb < 4; ++cb) {
    float bc = Blds[64 + cb * 16 + m];
    #pragma unroll
    for (int r = 0; r < 4; ++r) {
      float v = geluf(acc[cb][r] + bc);
      At[(quad * 4 + r) * 104 + cb * 16 + m] = (short)f2bf(v);
    }
  }
  run_layer<2, 4, 72>(At, Wlds + W2_OFF, m, quad, acc);
  #pragma unroll
  for (int cb = 0; cb < 4; ++cb) {
    float bc = Blds[128 + cb * 16 + m];
    #pragma unroll
    for (int r = 0; r < 4; ++r) {
      float v = geluf(acc[cb][r] + bc);
      At[(quad * 4 + r) * 104 + cb * 16 + m] = (short)f2bf(v);
    }
  }
  run_layer<2, 5, 72>(At, Wlds + W3_OFF, m, quad, acc);
  #pragma unroll
  for (int cb = 0; cb < 5; ++cb) {
    int col = cb * 16 + m;
    float bc = Blds[192 + col];
    #pragma unroll
    for (int r = 0; r < 4; ++r) {
      float v = acc[cb][r] + bc;
      int row = quad * 4 + r;
      if (col == 0) {
        float d = (v > 15.f) ? v : __logf(1.0f + __expf(v));
        outp[3 * Nrows + row0 + row] = d;
      } else if (col <= 64) {
        At[row * 104 + (col - 1)] = (short)f2bf(geluf(v));
      }
    }
  }

  __syncthreads();

  stageW<73, 64, 64, 104>(rw0, Wlds + R0_OFF, tid);
  stageW<64, 64, 64,  72>(rw1, Wlds + R1_OFF, tid);
  stageW<64,  3, 16,  72>(rw2, Wlds + R2_OFF, tid);
  stageB<64, 64>(rb0, Blds + 0,   tid);
  stageB<64, 64>(rb1, Blds + 64,  tid);
  stageB< 3, 16>(rb2, Blds + 128, tid);

  __syncthreads();

  run_layer<3, 4, 104>(At, Wlds + R0_OFF, m, quad, acc);
  #pragma unroll
  for (int cb = 0; cb < 4; ++cb) {
    float bc = Blds[0 + cb * 16 + m];
    #pragma unroll
    for (int r = 0; r < 4; ++r) {
      float v = geluf(acc[cb][r] + bc);
      At[(quad * 4 + r) * 104 + cb * 16 + m] = (short)f2bf(v);
    }
  }
  run_layer<2, 4, 72>(At, Wlds + R1_OFF, m, quad, acc);
  #pragma unroll
  for (int cb = 0; cb < 4; ++cb) {
    float bc = Blds[64 + cb * 16 + m];
    #pragma unroll
    for (int r = 0; r < 4; ++r) {
      float v = geluf(acc[cb][r] + bc);
      At[(quad * 4 + r) * 104 + cb * 16 + m] = (short)f2bf(v);
    }
  }
  run_layer<2, 1, 72>(At, Wlds + R2_OFF, m, quad, acc);
  {
    float bc = Blds[128 + m];
    #pragma unroll
    for (int r = 0; r < 4; ++r) {
      float v = acc[0][r] + bc;
      float s = __builtin_amdgcn_rcpf(1.0f + __expf(-v));
      if (m < 3) outp[(row0 + quad * 4 + r) * 3 + m] = s;
    }
  }
}

extern "C" void kernel_launch(void* const* d_in, const int* in_sizes, int n_in,
                              void* d_out, int out_size, void* d_ws, size_t ws_size,
                              hipStream_t stream) {
  ResParams rp;
  double b = exp((log(2048.0) - log(16.0)) / 23.0);
  for (int l = 0; l < LVL; ++l) rp.r[l] = (float)floor(16.0 * pow(b, (double)l));

  const float* pts  = (const float*)d_in[0];
  const float* dirs = (const float*)d_in[1];
  const float* tbl  = (const float*)d_in[2];
  float* outp = (float*)d_out;

  int n = in_sizes[0] / 3;                 // 524288
  int nent = LVL << 19;                    // 12.58M entries
  size_t img_reserve = 65536;              // Wimg 57344B + Bimg 1664B
  size_t tbl_b = (size_t)nent * 4u;        // 50.3 MB packed
  size_t full_need = img_reserve + tbl_b;

  short* Wimg = (short*)d_ws;
  float* Bimg = (float*)((char*)d_ws + 57344);
  unsigned* tblq = (unsigned*)((char*)d_ws + img_reserve);
  int blocks = n / 128;                    // 4096

  if (ws_size >= full_need) {
    prep_all<<<8 + 6144, 256, 0, stream>>>(
        (const float*)d_in[3],  (const float*)d_in[4],
        (const float*)d_in[5],  (const float*)d_in[6],
        (const float*)d_in[7],  (const float*)d_in[8],
        (const float*)d_in[9],  (const float*)d_in[10],
        (const float*)d_in[11], (const float*)d_in[12],
        (const float*)d_in[13], (const float*)d_in[14],
        (const float*)d_in[15], (const float*)d_in[16],
        Wimg, Bimg, tbl, tblq, nent, 1);
    nerf_block<true><<<blocks, 256, 0, stream>>>(
        pts, dirs, tbl, tblq, Wimg, Bimg, outp, n, rp);
  } else if (ws_size >= img_reserve) {
    prep_all<<<8, 256, 0, stream>>>(
        (const float*)d_in[3],  (const float*)d_in[4],
        (const float*)d_in[5],  (const float*)d_in[6],
        (const float*)d_in[7],  (const float*)d_in[8],
        (const float*)d_in[9],  (const float*)d_in[10],
        (const float*)d_in[11], (const float*)d_in[12],
        (const float*)d_in[13], (const float*)d_in[14],
        (const float*)d_in[15], (const float*)d_in[16],
        Wimg, Bimg, tbl, nullptr, nent, 0);
    nerf_block<false><<<blocks, 256, 0, stream>>>(
        pts, dirs, tbl, nullptr, Wimg, Bimg, outp, n, rp);
  } else {
    nerf_fused<<<n / 64, 256, 0, stream>>>(
        pts, dirs, tbl,
        (const float*)d_in[3],  (const float*)d_in[4],
        (const float*)d_in[5],  (const float*)d_in[6],
        (const float*)d_in[7],  (const float*)d_in[8],
        (const float*)d_in[9],  (const float*)d_in[10],
        (const float*)d_in[11], (const float*)d_in[12],
        (const float*)d_in[13], (const float*)d_in[14],
        (const float*)d_in[15], (const float*)d_in[16],
        outp, n, rp);
  }
}